// Round 1
// baseline (2344.308 us; speedup 1.0000x reference)
//
#include <hip/hip_runtime.h>

typedef _Float16 f16;
typedef _Float16 f16x8 __attribute__((ext_vector_type(8)));
typedef float f32x4 __attribute__((ext_vector_type(4)));

#define DHW 2688
#define HW_ 672

// ---------- weight split: fold BN scale, emit f16 hi/lo in [27][CO][CI], plus shift[CO] ----------
__global__ __launch_bounds__(256) void wsplit_k(
    const float* __restrict__ w, const float* __restrict__ convb,
    const float* __restrict__ bng, const float* __restrict__ bnb,
    const float* __restrict__ bnm, const float* __restrict__ bnv,
    f16* __restrict__ wh, f16* __restrict__ wl, float* __restrict__ shift,
    int CO, int CI)
{
    int idx = blockIdx.x * 256 + threadIdx.x;
    int total = CO * CI * 27;
    if (idx >= total) return;
    int ci = idx % CI; int t = idx / CI; int co = t % CO; int o = t / CO;
    float scale = bng[co] / sqrtf(bnv[co] + 1e-5f);
    float x = w[((long)co * CI + ci) * 27 + o] * scale;
    f16 h = (f16)x;
    wh[idx] = h;
    wl[idx] = (f16)(x - (float)h);
    if (o == 0 && ci == 0) shift[co] = (convb[co] - bnm[co]) * scale + bnb[co];
}

// ---------- implicit-GEMM 3x3x3 conv + folded BN + ReLU, fp16-split (3-product) MFMA ----------
// X: [16, CI, 2688] f32   Whi/Wlo: [27, CO, CI] f16   Y: [16, CO, 2688] f32
template<int CO, int CI, int BM, int TH, int WM, int WN>
__global__ __launch_bounds__(TH) void convk(
    const float* __restrict__ X, const f16* __restrict__ Whi,
    const f16* __restrict__ Wlo, const float* __restrict__ shift,
    float* __restrict__ Y)
{
    constexpr int BN = 128;
    constexpr int AG = BM * 5;              // A granules: BM rows x 5x16B (4 data + 1 pad)
    constexpr int AIT = (AG + TH - 1) / TH;
    constexpr int BGI = (BN * 4) / TH;      // B: 512 groups of 8 ci
    constexpr int WROWS = BM / WM;          // 64 in both configs

    __shared__ f16 Ah[AG * 8], Al[AG * 8];  // row stride 40 f16 (80B) -> conflict-light
    __shared__ f16 Bh[BN * 40], Bl[BN * 40];
    __shared__ float s_shift[BM];

    const int tid = threadIdx.x;
    const int lane = tid & 63, wid = tid >> 6;
    const int wm = wid / WN, wn = wid % WN;
    const int nbase = blockIdx.x * BN;
    const int cobase = blockIdx.y * BM;

    // per-thread B-staging coords (fixed for the whole block lifetime)
    const int nl = tid & (BN - 1);
    const int ngl0 = nbase + nl;
    const int bb = ngl0 / DHW;
    const int dhw0 = ngl0 % DHW;
    const int dd = dhw0 / HW_;
    const int hh = (dhw0 % HW_) / 32;
    const int ww = dhw0 & 31;

    if (tid < BM) s_shift[tid] = shift[cobase + tid];

    int aco[AIT], acis[AIT];
#pragma unroll
    for (int it2 = 0; it2 < AIT; ++it2) {
        int gl = it2 * TH + tid;
        aco[it2] = gl / 5;
        int gs = gl % 5;
        acis[it2] = (gs < 4) ? gs * 8 : 0;   // pad granule re-reads granule 0 (never consumed)
    }

    f32x4 acc[4][2];
    f32x4 zero = {0.f, 0.f, 0.f, 0.f};
#pragma unroll
    for (int i = 0; i < 4; ++i)
#pragma unroll
        for (int j = 0; j < 2; ++j) acc[i][j] = zero;

    const int arow = wm * WROWS + (lane & 15);
    const int koff = (lane >> 4) * 8;
    const int brow = wn * 32 + (lane & 15);

    for (int o = 0; o < 27; ++o) {
        const int od = o / 9 - 1, oh = (o / 3) % 3 - 1, ow = o % 3 - 1;
        const int d2 = dd + od, h2 = hh + oh, w2 = ww + ow;
        const bool val = ((unsigned)d2 < 4u) & ((unsigned)h2 < 21u) & ((unsigned)w2 < 32u);
        const long xoff = (long)bb * CI * DHW + (long)d2 * HW_ + h2 * 32 + w2;

        for (int ci0 = 0; ci0 < CI; ci0 += 32) {
            __syncthreads();
            // ---- stage A (pre-split f16 weights, reg-staged) ----
            const f16* wbh = Whi + ((long)o * CO + cobase) * CI + ci0;
            const f16* wbl = Wlo + ((long)o * CO + cobase) * CI + ci0;
#pragma unroll
            for (int it2 = 0; it2 < AIT; ++it2) {
                int gl = it2 * TH + tid;
                if (gl < AG) {
                    long so = (long)aco[it2] * CI + acis[it2];
                    *(f16x8*)&Ah[gl * 8] = *(const f16x8*)(wbh + so);
                    *(f16x8*)&Al[gl * 8] = *(const f16x8*)(wbl + so);
                }
            }
            // ---- stage B (f32 -> f16 hi/lo, shifted + masked) ----
#pragma unroll
            for (int it2 = 0; it2 < BGI; ++it2) {
                int cib = (it2 * TH + tid) >> 7;
                const float* xp = X + xoff + (long)(ci0 + cib * 8) * DHW;
                f16x8 hv, lv;
#pragma unroll
                for (int i = 0; i < 8; ++i) {
                    float v = val ? xp[(long)i * DHW] : 0.f;
                    f16 h = (f16)v;
                    hv[i] = h;
                    lv[i] = (f16)(v - (float)h);
                }
                *(f16x8*)&Bh[nl * 40 + cib * 8] = hv;
                *(f16x8*)&Bl[nl * 40 + cib * 8] = lv;
            }
            __syncthreads();
            // ---- fragments + MFMA (hi*hi + hi*lo + lo*hi) ----
            f16x8 af_h[4], af_l[4], bf_h[2], bf_l[2];
#pragma unroll
            for (int ni = 0; ni < 2; ++ni) {
                bf_h[ni] = *(const f16x8*)&Bh[(brow + ni * 16) * 40 + koff];
                bf_l[ni] = *(const f16x8*)&Bl[(brow + ni * 16) * 40 + koff];
            }
#pragma unroll
            for (int mi = 0; mi < 4; ++mi) {
                af_h[mi] = *(const f16x8*)&Ah[(arow + mi * 16) * 40 + koff];
                af_l[mi] = *(const f16x8*)&Al[(arow + mi * 16) * 40 + koff];
            }
#pragma unroll
            for (int mi = 0; mi < 4; ++mi)
#pragma unroll
                for (int ni = 0; ni < 2; ++ni) {
                    acc[mi][ni] = __builtin_amdgcn_mfma_f32_16x16x32_f16(af_h[mi], bf_h[ni], acc[mi][ni], 0, 0, 0);
                    acc[mi][ni] = __builtin_amdgcn_mfma_f32_16x16x32_f16(af_h[mi], bf_l[ni], acc[mi][ni], 0, 0, 0);
                    acc[mi][ni] = __builtin_amdgcn_mfma_f32_16x16x32_f16(af_l[mi], bf_h[ni], acc[mi][ni], 0, 0, 0);
                }
        }
    }

    // ---- epilogue: + shift, ReLU, store ----
#pragma unroll
    for (int ni = 0; ni < 2; ++ni) {
        int n_l = wn * 32 + ni * 16 + (lane & 15);
        int ngl = nbase + n_l;
        int b2 = ngl / DHW;
        int dhw2 = ngl % DHW;
        float* yb = Y + (long)b2 * CO * DHW + dhw2;
#pragma unroll
        for (int mi = 0; mi < 4; ++mi) {
            int co_l = wm * WROWS + mi * 16 + (lane >> 4) * 4;
#pragma unroll
            for (int r = 0; r < 4; ++r) {
                float v = acc[mi][ni][r] + s_shift[co_l + r];
                v = fmaxf(v, 0.f);
                yb[(long)(cobase + co_l + r) * DHW] = v;
            }
        }
    }
}

// ---------- global average pool (partial: 32 channels per block) ----------
__global__ __launch_bounds__(256) void pool_k(const float* __restrict__ F, float* __restrict__ pooled)
{
    int b = blockIdx.x, cblk = blockIdx.y;
    int tid = threadIdx.x, lane = tid & 63, wid = tid >> 6;
    const float* Fb = F + ((long)b * 512 + cblk * 32) * DHW;
    for (int c = wid; c < 32; c += 4) {
        const float* row = Fb + (long)c * DHW;
        float s = 0.f;
        for (int i = lane; i < DHW; i += 64) s += row[i];
#pragma unroll
        for (int o2 = 32; o2; o2 >>= 1) s += __shfl_down(s, o2);
        if (lane == 0) pooled[b * 512 + cblk * 32 + c] = s / 2688.f;
    }
}

// ---------- classification / severity heads ----------
__global__ __launch_bounds__(128) void head2_k(const float* __restrict__ pooled,
    const float* __restrict__ cw, const float* __restrict__ cb,
    const float* __restrict__ sw, const float* __restrict__ sb,
    float* __restrict__ out)
{
    int t = threadIdx.x;
    if (t >= 96) return;
    int b = t & 15, o = t >> 4;
    const float* p = pooled + b * 512;
    const float* wr = (o < 2) ? (cw + o * 512) : (sw + (o - 2) * 512);
    float s = 0.f;
    for (int i = 0; i < 512; ++i) s += p[i] * wr[i];
    if (o < 2) out[b * 2 + o] = s + cb[o];
    else out[32 + b * 4 + (o - 2)] = s + sb[o - 2];
}

// ---------- conv3 (1x1x1) + time-mean + decode ----------
__global__ __launch_bounds__(256) void dec_k(const float* __restrict__ X2,
    const float* __restrict__ w3, const float* __restrict__ b3,
    float* __restrict__ boxes, float* __restrict__ conf, float* __restrict__ cls)
{
    __shared__ float swt[1024];
    int tid = threadIdx.x;
    for (int i = tid; i < 1024; i += 256) swt[i] = w3[i];
    __syncthreads();
    int idx = blockIdx.x * 256 + tid;           // 0..10751 (= 16*672 exactly)
    int b = idx / HW_, hw = idx % HW_;
    int h = hw >> 5, w = hw & 31;
    const float* xb = X2 + (long)b * 128 * DHW + hw;
    float a[8];
#pragma unroll
    for (int c = 0; c < 8; ++c) a[c] = 0.f;
    for (int ci = 0; ci < 128; ++ci) {
        const float* p = xb + (long)ci * DHW;
        float xv = p[0] + p[672] + p[1344] + p[2016];
#pragma unroll
        for (int c = 0; c < 8; ++c) a[c] = fmaf(swt[c * 128 + ci], xv, a[c]);
    }
    float raw[8];
#pragma unroll
    for (int c = 0; c < 8; ++c) raw[c] = a[c] * 0.25f + b3[c];
    float xo = 1.f / (1.f + expf(-raw[0]));
    float yo = 1.f / (1.f + expf(-raw[1]));
    float wsc = expf(raw[2]);
    float hsc = expf(raw[3]);
    float obj = 1.f / (1.f + expf(-raw[4]));
    float mx = fmaxf(raw[5], fmaxf(raw[6], raw[7]));
    float e0 = expf(raw[5] - mx), e1 = expf(raw[6] - mx), e2 = expf(raw[7] - mx);
    float se = e0 + e1 + e2;
    int bi = 0; float bs = e0;
    if (e1 > bs) { bi = 1; bs = e1; }
    if (e2 > bs) { bi = 2; bs = e2; }
    float best = bs / se;
    float gx = (float)w * (1.f / 32.f);
    float gy = (float)h / 21.f;
    float xc = (gx + xo) * 512.f;
    float yc = (gy + yo) * 328.f;
    float bw = 0.2f * wsc * 512.f;
    float bh = 0.29f * hsc * 328.f;
    long bo = (long)idx * 4;
    boxes[bo + 0] = xc - bw * 0.5f;
    boxes[bo + 1] = yc - bh * 0.5f;
    boxes[bo + 2] = xc + bw * 0.5f;
    boxes[bo + 3] = yc + bh * 0.5f;
    conf[idx] = obj * best;
    cls[idx] = (float)bi;
}

// ---------- greedy NMS, one block per image, jnp.argmax (first-max) semantics ----------
__global__ __launch_bounds__(256) void nms_k(const float* __restrict__ boxes,
    const float* __restrict__ conf, const float* __restrict__ cls,
    float* __restrict__ out)
{
    int b = blockIdx.x, tid = threadIdx.x;
    int lane = tid & 63, wid = tid >> 6;
    __shared__ float sc[HW_];
    __shared__ float4 sb[HW_];
    __shared__ float sk[HW_];
    __shared__ float rv[4];
    __shared__ int ri[4];
    const float* cf = conf + b * HW_;
    const float4* bx = (const float4*)(boxes + (long)b * HW_ * 4);
    for (int i = tid; i < HW_; i += 256) {
        float c = cf[i];
        sc[i] = (c > 0.2f) ? c : -1.f;
        sb[i] = bx[i];
        sk[i] = cls[b * HW_ + i];
    }
    __syncthreads();
    for (int it = 0; it < 10; ++it) {
        float bv = -2.f; int bidx = 1 << 20;
        for (int i = tid; i < HW_; i += 256) {
            float v = sc[i];
            if (v > bv || (v == bv && i < bidx)) { bv = v; bidx = i; }
        }
#pragma unroll
        for (int o2 = 32; o2; o2 >>= 1) {
            float ov = __shfl_down(bv, o2);
            int oi = __shfl_down(bidx, o2);
            if (ov > bv || (ov == bv && oi < bidx)) { bv = ov; bidx = oi; }
        }
        if (lane == 0) { rv[wid] = bv; ri[wid] = bidx; }
        __syncthreads();
        if (tid == 0) {
#pragma unroll
            for (int wv = 1; wv < 4; ++wv)
                if (rv[wv] > rv[0] || (rv[wv] == rv[0] && ri[wv] < ri[0])) { rv[0] = rv[wv]; ri[0] = ri[wv]; }
        }
        __syncthreads();
        float s = rv[0]; int ix = ri[0];
        float4 wb = sb[ix];
        bool valid = s > 0.f;
        for (int i = tid; i < HW_; i += 256) {
            float4 ob = sb[i];
            float x1 = fmaxf(wb.x, ob.x), y1 = fmaxf(wb.y, ob.y);
            float x2 = fminf(wb.z, ob.z), y2 = fminf(wb.w, ob.w);
            float inter = fmaxf(x2 - x1, 0.f) * fmaxf(y2 - y1, 0.f);
            float a1 = (wb.z - wb.x) * (wb.w - wb.y);
            float a2 = (ob.z - ob.x) * (ob.w - ob.y);
            float iou = inter / fmaxf(a1 + a2 - inter, 1e-9f);
            if (iou > 0.3f || i == ix) sc[i] = -1.f;
        }
        if (tid == 0) {
            float vf = valid ? 1.f : 0.f;
            float* ob2 = out + 96 + (b * 10 + it) * 4;
            ob2[0] = wb.x * vf; ob2[1] = wb.y * vf; ob2[2] = wb.z * vf; ob2[3] = wb.w * vf;
            out[736 + b * 10 + it] = valid ? s : 0.f;
            out[896 + b * 10 + it] = valid ? sk[ix] : -1.f;
        }
        __syncthreads();
    }
}

extern "C" void kernel_launch(void* const* d_in, const int* in_sizes, int n_in,
                              void* d_out, int out_size, void* d_ws, size_t ws_size,
                              hipStream_t stream)
{
    const float* features = (const float*)d_in[0];
    const float* c1w = (const float*)d_in[1];
    const float* c1b = (const float*)d_in[2];
    const float* g1 = (const float*)d_in[3];
    const float* b1 = (const float*)d_in[4];
    const float* m1 = (const float*)d_in[5];
    const float* v1 = (const float*)d_in[6];
    const float* c2w = (const float*)d_in[7];
    const float* c2b = (const float*)d_in[8];
    const float* g2 = (const float*)d_in[9];
    const float* b2 = (const float*)d_in[10];
    const float* m2 = (const float*)d_in[11];
    const float* v2 = (const float*)d_in[12];
    const float* c3w = (const float*)d_in[13];
    const float* c3b = (const float*)d_in[14];
    const float* clw = (const float*)d_in[15];
    const float* clb = (const float*)d_in[16];
    const float* svw = (const float*)d_in[17];
    const float* svb = (const float*)d_in[18];
    float* out = (float*)d_out;

    char* wsp = (char*)d_ws;
    size_t off = 0;
    auto alloc = [&](size_t bytes) -> char* {
        char* p = wsp + off;
        off += (bytes + 255) & ~(size_t)255;
        return p;
    };
    f16* w1h = (f16*)alloc(27ULL * 256 * 512 * 2);
    f16* w1l = (f16*)alloc(27ULL * 256 * 512 * 2);
    f16* w2h = (f16*)alloc(27ULL * 128 * 256 * 2);
    f16* w2l = (f16*)alloc(27ULL * 128 * 256 * 2);
    float* sh1 = (float*)alloc(256 * 4);
    float* sh2 = (float*)alloc(128 * 4);
    float* act1 = (float*)alloc(16ULL * 256 * DHW * 4);
    float* act2 = (float*)alloc(16ULL * 128 * DHW * 4);
    float* pooled = (float*)alloc(16 * 512 * 4);
    float* bxs = (float*)alloc(16ULL * HW_ * 4 * 4);
    float* cnf = (float*)alloc(16 * HW_ * 4);
    float* clsv = (float*)alloc(16 * HW_ * 4);

    hipLaunchKernelGGL(wsplit_k, dim3((256 * 512 * 27 + 255) / 256), dim3(256), 0, stream,
                       c1w, c1b, g1, b1, m1, v1, w1h, w1l, sh1, 256, 512);
    hipLaunchKernelGGL(wsplit_k, dim3((128 * 256 * 27 + 255) / 256), dim3(256), 0, stream,
                       c2w, c2b, g2, b2, m2, v2, w2h, w2l, sh2, 128, 256);
    hipLaunchKernelGGL(pool_k, dim3(16, 16), dim3(256), 0, stream, features, pooled);
    hipLaunchKernelGGL(head2_k, dim3(1), dim3(128), 0, stream, pooled, clw, clb, svw, svb, out);
    hipLaunchKernelGGL((convk<256, 512, 128, 512, 2, 4>), dim3(336, 2), dim3(512), 0, stream,
                       features, w1h, w1l, sh1, act1);
    hipLaunchKernelGGL((convk<128, 256, 64, 256, 1, 4>), dim3(336, 2), dim3(256), 0, stream,
                       act1, w2h, w2l, sh2, act2);
    hipLaunchKernelGGL(dec_k, dim3(42), dim3(256), 0, stream, act2, c3w, c3b, bxs, cnf, clsv);
    hipLaunchKernelGGL(nms_k, dim3(16), dim3(256), 0, stream, bxs, cnf, clsv, out);
}

// Round 4
// 1401.709 us; speedup vs baseline: 1.6725x; 1.6725x over previous
//
#include <hip/hip_runtime.h>

typedef _Float16 f16;
typedef _Float16 f16x8 __attribute__((ext_vector_type(8)));
typedef float f32x4 __attribute__((ext_vector_type(4)));

#define DHW 2688
#define HW_ 672

__device__ __forceinline__ void gload16(const void* g, void* l) {
    __builtin_amdgcn_global_load_lds((const __attribute__((address_space(1))) void*)g,
                                     (__attribute__((address_space(3))) void*)l, 16, 0, 0);
}

// ---------- zero the halo pages (ws is poisoned 0xAA before every launch) ----------
__global__ __launch_bounds__(256) void init_k(f16* a, f16* b, f16* c, f16* d)
{
    int t = threadIdx.x;
    a[2 * t] = (f16)0.f; a[2 * t + 1] = (f16)0.f;
    b[2 * t] = (f16)0.f; b[2 * t + 1] = (f16)0.f;
    c[2 * t] = (f16)0.f; c[2 * t + 1] = (f16)0.f;
    d[2 * t] = (f16)0.f; d[2 * t + 1] = (f16)0.f;
}

// ---------- weight split: fold BN scale, emit f16 hi/lo in [27][CO][CI], plus shift[CO] ----------
__global__ __launch_bounds__(256) void wsplit_k(
    const float* __restrict__ w, const float* __restrict__ convb,
    const float* __restrict__ bng, const float* __restrict__ bnb,
    const float* __restrict__ bnm, const float* __restrict__ bnv,
    f16* __restrict__ wh, f16* __restrict__ wl, float* __restrict__ shift,
    int CO, int CI)
{
    int idx = blockIdx.x * 256 + threadIdx.x;
    int total = CO * CI * 27;
    if (idx >= total) return;
    int ci = idx % CI; int t = idx / CI; int co = t % CO; int o = t / CO;
    float scale = bng[co] / sqrtf(bnv[co] + 1e-5f);
    float x = w[((long)co * CI + ci) * 27 + o] * scale;
    f16 h = (f16)x;
    wh[idx] = h;
    wl[idx] = (f16)(x - (float)h);
    if (o == 0 && ci == 0) shift[co] = (convb[co] - bnm[co]) * scale + bnb[co];
}

// ---------- feature split+transpose: [b][ci][dhw] f32 -> [b][dhw][ci] f16 hi/lo ----------
__global__ __launch_bounds__(256) void fsplit_k(const float* __restrict__ X,
                                                f16* __restrict__ Fh, f16* __restrict__ Fl)
{
    __shared__ float s[64][65];
    const int t = threadIdx.x;
    const int dhw0 = blockIdx.x * 64, ci0 = blockIdx.y * 64, b = blockIdx.z;
    const int d = t & 63, c0 = t >> 6;
#pragma unroll
    for (int p = 0; p < 16; ++p) {
        int c = p * 4 + c0;
        s[c][d] = X[((long)(b * 512 + ci0 + c)) * DHW + dhw0 + d];
    }
    __syncthreads();
#pragma unroll
    for (int p = 0; p < 2; ++p) {
        int dd = (t >> 3) + p * 32, g = t & 7;
        f16x8 hv, lv;
#pragma unroll
        for (int j = 0; j < 8; ++j) {
            float v = s[g * 8 + j][dd];
            f16 h = (f16)v;
            hv[j] = h;
            lv[j] = (f16)(v - (float)h);
        }
        long oidx = ((long)b * DHW + dhw0 + dd) * 512 + ci0 + g * 8;
        *(f16x8*)&Fh[oidx] = hv;
        *(f16x8*)&Fl[oidx] = lv;
    }
}

// ---------- implicit-GEMM 3x3x3 conv + folded BN + ReLU, fp16-split (3-product) MFMA ----------
// Xh/Xl: [b][dhw][CI] f16 (tail zero page at ZOFF)   Whi/Wlo: [27][CO][CI] f16
// OUTS=1: write Yh/Yl f16 [b][dhw][CO]   OUTS=0: write Yf f32 [b][dhw][CO]
template<int CO, int CI, int BM, int BN, int TH, int WM, int WN, int OUTS>
__global__ __launch_bounds__(TH, (TH == 512) ? 4 : 3) void convk(
    const f16* __restrict__ Xh, const f16* __restrict__ Xl,
    const f16* __restrict__ Whi, const f16* __restrict__ Wlo,
    const float* __restrict__ shift, long ZOFF,
    f16* __restrict__ Yh, f16* __restrict__ Yl, float* __restrict__ Yf)
{
    static_assert(BN == 128, "grid.x mapping assumes BN==128");
    constexpr int AIT = BM * 8 / TH;   // A granules per array per thread
    constexpr int BIT = BN * 8 / TH;
    constexpr int MI = (BM / WM) / 16;
    constexpr int NI = (BN / WN) / 16;

    __shared__ __align__(16) char sm[(BM + BN) * 256];
    f16* Ah = (f16*)sm;
    f16* Al = Ah + BM * 64;
    f16* Bh = Al + BM * 64;
    f16* Bl = Bh + BN * 64;
    __shared__ float s_shift[BM];

    const int tid = threadIdx.x, lane = tid & 63, wid = tid >> 6;
    const int wm = wid / WN, wn = wid % WN;
    const int wmbase = wm * (BM / WM), wnbase = wn * (BN / WN);
    const int kg = lane >> 4;
    const int nb = blockIdx.x;
    const int bimg = nb / 21;
    const int dhw0 = (nb % 21) * BN;
    const int cobase = blockIdx.y * BM;

    if (tid < BM) s_shift[tid] = shift[cobase + tid];

    // per-thread staging descriptors
    int a_co[AIT], a_cig8[AIT], a_ldsg[AIT];
#pragma unroll
    for (int it = 0; it < AIT; ++it) {
        int g = it * TH + tid;
        a_co[it] = g >> 3;
        a_cig8[it] = ((g & 7) ^ (a_co[it] & 7)) << 3;
        a_ldsg[it] = (it * TH + (tid & ~63)) * 8;
    }
    int b_cig8[BIT], b_ldsg[BIT], b_dd[BIT], b_hh[BIT], b_ww[BIT];
#pragma unroll
    for (int it = 0; it < BIT; ++it) {
        int g = it * TH + tid;
        int n = g >> 3;
        b_cig8[it] = ((g & 7) ^ (n & 7)) << 3;
        b_ldsg[it] = (it * TH + (tid & ~63)) * 8;
        int ng = dhw0 + n;
        b_dd[it] = ng / HW_;
        int r = ng % HW_;
        b_hh[it] = r >> 5;
        b_ww[it] = r & 31;
    }

    f32x4 acc[MI][NI];
    f32x4 zero = {0.f, 0.f, 0.f, 0.f};
#pragma unroll
    for (int i = 0; i < MI; ++i)
#pragma unroll
        for (int j = 0; j < NI; ++j) acc[i][j] = zero;

    for (int o = 0; o < 27; ++o) {
        const int od = o / 9 - 1, ohh = (o / 3) % 3 - 1, oww = o % 3 - 1;
        int aoff[AIT];
        long boff[BIT];
#pragma unroll
        for (int it = 0; it < AIT; ++it)
            aoff[it] = (o * CO + cobase + a_co[it]) * CI + a_cig8[it];
#pragma unroll
        for (int it = 0; it < BIT; ++it) {
            int d2 = b_dd[it] + od, h2 = b_hh[it] + ohh, w2 = b_ww[it] + oww;
            bool val = ((unsigned)d2 < 4u) & ((unsigned)h2 < 21u) & ((unsigned)w2 < 32u);
            boff[it] = val ? ((long)(bimg * DHW + d2 * HW_ + h2 * 32 + w2) * CI + b_cig8[it])
                           : ZOFF;
        }
        for (int ci0 = 0; ci0 < CI; ci0 += 64) {
            __syncthreads();
#pragma unroll
            for (int it = 0; it < AIT; ++it) {
                gload16(Whi + aoff[it] + ci0, Ah + a_ldsg[it]);
                gload16(Wlo + aoff[it] + ci0, Al + a_ldsg[it]);
            }
#pragma unroll
            for (int it = 0; it < BIT; ++it) {
                gload16(Xh + boff[it] + ci0, Bh + b_ldsg[it]);
                gload16(Xl + boff[it] + ci0, Bl + b_ldsg[it]);
            }
            __syncthreads();
#pragma unroll
            for (int ks = 0; ks < 2; ++ks) {
                f16x8 ah[MI], al[MI], bh[NI], bl[NI];
#pragma unroll
                for (int mi = 0; mi < MI; ++mi) {
                    int row = wmbase + mi * 16 + (lane & 15);
                    int pos = (((ks << 2) | kg) ^ (row & 7)) << 3;
                    ah[mi] = *(const f16x8*)&Ah[row * 64 + pos];
                    al[mi] = *(const f16x8*)&Al[row * 64 + pos];
                }
#pragma unroll
                for (int ni = 0; ni < NI; ++ni) {
                    int row = wnbase + ni * 16 + (lane & 15);
                    int pos = (((ks << 2) | kg) ^ (row & 7)) << 3;
                    bh[ni] = *(const f16x8*)&Bh[row * 64 + pos];
                    bl[ni] = *(const f16x8*)&Bl[row * 64 + pos];
                }
#pragma unroll
                for (int mi = 0; mi < MI; ++mi)
#pragma unroll
                    for (int ni = 0; ni < NI; ++ni) {
                        acc[mi][ni] = __builtin_amdgcn_mfma_f32_16x16x32_f16(ah[mi], bh[ni], acc[mi][ni], 0, 0, 0);
                        acc[mi][ni] = __builtin_amdgcn_mfma_f32_16x16x32_f16(ah[mi], bl[ni], acc[mi][ni], 0, 0, 0);
                        acc[mi][ni] = __builtin_amdgcn_mfma_f32_16x16x32_f16(al[mi], bh[ni], acc[mi][ni], 0, 0, 0);
                    }
            }
        }
    }

    // ---- epilogue: + shift, ReLU, LDS-transpose, coalesced store ----
    const long nrow0 = (long)bimg * DHW + dhw0;
    __syncthreads();
    if (OUTS) {
        f16* T = (f16*)sm;
#pragma unroll
        for (int part = 0; part < 2; ++part) {
#pragma unroll
            for (int mi = 0; mi < MI; ++mi)
#pragma unroll
                for (int ni = 0; ni < NI; ++ni) {
                    int n_l = wnbase + ni * 16 + (lane & 15);
                    int co_l = wmbase + mi * 16 + ((lane >> 4) << 2);
#pragma unroll
                    for (int r = 0; r < 4; ++r) {
                        float v = acc[mi][ni][r] + s_shift[co_l + r];
                        v = fmaxf(v, 0.f);
                        f16 h = (f16)v;
                        T[n_l * BM + co_l + r] = part ? (f16)(v - (float)h) : h;
                    }
                }
            __syncthreads();
            f16* Yp = part ? Yl : Yh;
#pragma unroll
            for (int wg = 0; wg < BN * BM / 8 / TH; ++wg) {
                int g = wg * TH + tid;
                int n = g / (BM / 8), gg = g % (BM / 8);
                *(f16x8*)(Yp + (nrow0 + n) * CO + cobase + gg * 8) = *(const f16x8*)&T[n * BM + gg * 8];
            }
            __syncthreads();
        }
    } else {
        float* T = (float*)sm;
#pragma unroll
        for (int mi = 0; mi < MI; ++mi)
#pragma unroll
            for (int ni = 0; ni < NI; ++ni) {
                int n_l = wnbase + ni * 16 + (lane & 15);
                int co_l = wmbase + mi * 16 + ((lane >> 4) << 2);
#pragma unroll
                for (int r = 0; r < 4; ++r) {
                    float v = acc[mi][ni][r] + s_shift[co_l + r];
                    T[n_l * BM + co_l + r] = fmaxf(v, 0.f);
                }
            }
        __syncthreads();
#pragma unroll
        for (int wg = 0; wg < BN * BM / 4 / TH; ++wg) {
            int g = wg * TH + tid;
            int n = g / (BM / 4), gg = g % (BM / 4);
            *(float4*)(Yf + (nrow0 + n) * CO + cobase + gg * 4) = *(const float4*)&T[n * BM + gg * 4];
        }
    }
}

// ---------- global average pool (reads original [b][ci][dhw] features) ----------
__global__ __launch_bounds__(256) void pool_k(const float* __restrict__ F, float* __restrict__ pooled)
{
    int b = blockIdx.x, cblk = blockIdx.y;
    int tid = threadIdx.x, lane = tid & 63, wid = tid >> 6;
    const float* Fb = F + ((long)b * 512 + cblk * 32) * DHW;
    for (int c = wid; c < 32; c += 4) {
        const float* row = Fb + (long)c * DHW;
        float s = 0.f;
        for (int i = lane; i < DHW; i += 64) s += row[i];
#pragma unroll
        for (int o2 = 32; o2; o2 >>= 1) s += __shfl_down(s, o2);
        if (lane == 0) pooled[b * 512 + cblk * 32 + c] = s / 2688.f;
    }
}

// ---------- classification / severity heads ----------
__global__ __launch_bounds__(128) void head2_k(const float* __restrict__ pooled,
    const float* __restrict__ cw, const float* __restrict__ cb,
    const float* __restrict__ sw, const float* __restrict__ sb,
    float* __restrict__ out)
{
    int t = threadIdx.x;
    if (t >= 96) return;
    int b = t & 15, o = t >> 4;
    const float* p = pooled + b * 512;
    const float* wr = (o < 2) ? (cw + o * 512) : (sw + (o - 2) * 512);
    float s = 0.f;
    for (int i = 0; i < 512; ++i) s += p[i] * wr[i];
    if (o < 2) out[b * 2 + o] = s + cb[o];
    else out[32 + b * 4 + (o - 2)] = s + sb[o - 2];
}

// ---------- conv3 (1x1x1) + time-mean + decode  (X2: [b][dhw][128] f32) ----------
__global__ __launch_bounds__(256) void dec_k(const float* __restrict__ X2,
    const float* __restrict__ w3, const float* __restrict__ b3,
    float* __restrict__ boxes, float* __restrict__ conf, float* __restrict__ cls)
{
    __shared__ float swt[1024];
    int tid = threadIdx.x;
    for (int i = tid; i < 1024; i += 256) swt[i] = w3[i];
    __syncthreads();
    int idx = blockIdx.x * 256 + tid;           // 0..10751
    int b = idx / HW_, hw = idx % HW_;
    int h = hw >> 5, w = hw & 31;
    float a[8];
#pragma unroll
    for (int c = 0; c < 8; ++c) a[c] = 0.f;
#pragma unroll
    for (int t4 = 0; t4 < 4; ++t4) {
        const float4* xp = (const float4*)(X2 + ((long)b * DHW + t4 * HW_ + hw) * 128);
#pragma unroll 8
        for (int cg = 0; cg < 32; ++cg) {
            float4 x = xp[cg];
#pragma unroll
            for (int c = 0; c < 8; ++c) {
                a[c] = fmaf(swt[c * 128 + cg * 4 + 0], x.x, a[c]);
                a[c] = fmaf(swt[c * 128 + cg * 4 + 1], x.y, a[c]);
                a[c] = fmaf(swt[c * 128 + cg * 4 + 2], x.z, a[c]);
                a[c] = fmaf(swt[c * 128 + cg * 4 + 3], x.w, a[c]);
            }
        }
    }
    float raw[8];
#pragma unroll
    for (int c = 0; c < 8; ++c) raw[c] = a[c] * 0.25f + b3[c];
    float xo = 1.f / (1.f + expf(-raw[0]));
    float yo = 1.f / (1.f + expf(-raw[1]));
    float wsc = expf(raw[2]);
    float hsc = expf(raw[3]);
    float obj = 1.f / (1.f + expf(-raw[4]));
    float mx = fmaxf(raw[5], fmaxf(raw[6], raw[7]));
    float e0 = expf(raw[5] - mx), e1 = expf(raw[6] - mx), e2 = expf(raw[7] - mx);
    float se = e0 + e1 + e2;
    int bi = 0; float bs = e0;
    if (e1 > bs) { bi = 1; bs = e1; }
    if (e2 > bs) { bi = 2; bs = e2; }
    float best = bs / se;
    float gx = (float)w * (1.f / 32.f);
    float gy = (float)h / 21.f;
    float xc = (gx + xo) * 512.f;
    float yc = (gy + yo) * 328.f;
    float bw = 0.2f * wsc * 512.f;
    float bh = 0.29f * hsc * 328.f;
    long bo = (long)idx * 4;
    boxes[bo + 0] = xc - bw * 0.5f;
    boxes[bo + 1] = yc - bh * 0.5f;
    boxes[bo + 2] = xc + bw * 0.5f;
    boxes[bo + 3] = yc + bh * 0.5f;
    conf[idx] = obj * best;
    cls[idx] = (float)bi;
}

// ---------- greedy NMS, one block per image, jnp.argmax (first-max) semantics ----------
__global__ __launch_bounds__(256) void nms_k(const float* __restrict__ boxes,
    const float* __restrict__ conf, const float* __restrict__ cls,
    float* __restrict__ out)
{
    int b = blockIdx.x, tid = threadIdx.x;
    int lane = tid & 63, wid = tid >> 6;
    __shared__ float sc[HW_];
    __shared__ float4 sb[HW_];
    __shared__ float sk[HW_];
    __shared__ float rv[4];
    __shared__ int ri[4];
    const float* cf = conf + b * HW_;
    const float4* bx = (const float4*)(boxes + (long)b * HW_ * 4);
    for (int i = tid; i < HW_; i += 256) {
        float c = cf[i];
        sc[i] = (c > 0.2f) ? c : -1.f;
        sb[i] = bx[i];
        sk[i] = cls[b * HW_ + i];
    }
    __syncthreads();
    for (int it = 0; it < 10; ++it) {
        float bv = -2.f; int bidx = 1 << 20;
        for (int i = tid; i < HW_; i += 256) {
            float v = sc[i];
            if (v > bv || (v == bv && i < bidx)) { bv = v; bidx = i; }
        }
#pragma unroll
        for (int o2 = 32; o2; o2 >>= 1) {
            float ov = __shfl_down(bv, o2);
            int oi = __shfl_down(bidx, o2);
            if (ov > bv || (ov == bv && oi < bidx)) { bv = ov; bidx = oi; }
        }
        if (lane == 0) { rv[wid] = bv; ri[wid] = bidx; }
        __syncthreads();
        if (tid == 0) {
#pragma unroll
            for (int wv = 1; wv < 4; ++wv)
                if (rv[wv] > rv[0] || (rv[wv] == rv[0] && ri[wv] < ri[0])) { rv[0] = rv[wv]; ri[0] = ri[wv]; }
        }
        __syncthreads();
        float s = rv[0]; int ix = ri[0];
        float4 wb = sb[ix];
        bool valid = s > 0.f;
        for (int i = tid; i < HW_; i += 256) {
            float4 ob = sb[i];
            float x1 = fmaxf(wb.x, ob.x), y1 = fmaxf(wb.y, ob.y);
            float x2 = fminf(wb.z, ob.z), y2 = fminf(wb.w, ob.w);
            float inter = fmaxf(x2 - x1, 0.f) * fmaxf(y2 - y1, 0.f);
            float a1 = (wb.z - wb.x) * (wb.w - wb.y);
            float a2 = (ob.z - ob.x) * (ob.w - ob.y);
            float iou = inter / fmaxf(a1 + a2 - inter, 1e-9f);
            if (iou > 0.3f || i == ix) sc[i] = -1.f;
        }
        if (tid == 0) {
            float vf = valid ? 1.f : 0.f;
            float* ob2 = out + 96 + (b * 10 + it) * 4;
            ob2[0] = wb.x * vf; ob2[1] = wb.y * vf; ob2[2] = wb.z * vf; ob2[3] = wb.w * vf;
            out[736 + b * 10 + it] = valid ? s : 0.f;
            out[896 + b * 10 + it] = valid ? sk[ix] : -1.f;
        }
        __syncthreads();
    }
}

extern "C" void kernel_launch(void* const* d_in, const int* in_sizes, int n_in,
                              void* d_out, int out_size, void* d_ws, size_t ws_size,
                              hipStream_t stream)
{
    const float* features = (const float*)d_in[0];
    const float* c1w = (const float*)d_in[1];
    const float* c1b = (const float*)d_in[2];
    const float* g1 = (const float*)d_in[3];
    const float* b1 = (const float*)d_in[4];
    const float* m1 = (const float*)d_in[5];
    const float* v1 = (const float*)d_in[6];
    const float* c2w = (const float*)d_in[7];
    const float* c2b = (const float*)d_in[8];
    const float* g2 = (const float*)d_in[9];
    const float* b2 = (const float*)d_in[10];
    const float* m2 = (const float*)d_in[11];
    const float* v2 = (const float*)d_in[12];
    const float* c3w = (const float*)d_in[13];
    const float* c3b = (const float*)d_in[14];
    const float* clw = (const float*)d_in[15];
    const float* clb = (const float*)d_in[16];
    const float* svw = (const float*)d_in[17];
    const float* svb = (const float*)d_in[18];
    float* out = (float*)d_out;

    char* wsp = (char*)d_ws;
    size_t off = 0;
    auto alloc = [&](size_t bytes) -> char* {
        char* p = wsp + off;
        off += (bytes + 255) & ~(size_t)255;
        return p;
    };
    const long NPIX = 16L * DHW;                 // 43008
    const long ZF = NPIX * 512;                  // f16 idx of feature zero page
    const long ZA = NPIX * 256;                  // f16 idx of act1 zero page

    f16* w1h = (f16*)alloc(27ULL * 256 * 512 * 2);
    f16* w1l = (f16*)alloc(27ULL * 256 * 512 * 2);
    f16* w2h = (f16*)alloc(27ULL * 128 * 256 * 2);
    f16* w2l = (f16*)alloc(27ULL * 128 * 256 * 2);
    float* sh1 = (float*)alloc(256 * 4);
    float* sh2 = (float*)alloc(128 * 4);
    f16* Fh = (f16*)alloc(ZF * 2 + 1024);
    f16* Fl = (f16*)alloc(ZF * 2 + 1024);
    f16* a1h = (f16*)alloc(ZA * 2 + 1024);
    f16* a1l = (f16*)alloc(ZA * 2 + 1024);
    float* act2 = (float*)alloc((size_t)NPIX * 128 * 4);
    float* pooled = (float*)alloc(16 * 512 * 4);
    float* bxs = (float*)alloc(16ULL * HW_ * 4 * 4);
    float* cnf = (float*)alloc(16 * HW_ * 4);
    float* clsv = (float*)alloc(16 * HW_ * 4);

    hipLaunchKernelGGL(init_k, dim3(1), dim3(256), 0, stream, Fh + ZF, Fl + ZF, a1h + ZA, a1l + ZA);
    hipLaunchKernelGGL(wsplit_k, dim3((256 * 512 * 27 + 255) / 256), dim3(256), 0, stream,
                       c1w, c1b, g1, b1, m1, v1, w1h, w1l, sh1, 256, 512);
    hipLaunchKernelGGL(wsplit_k, dim3((128 * 256 * 27 + 255) / 256), dim3(256), 0, stream,
                       c2w, c2b, g2, b2, m2, v2, w2h, w2l, sh2, 128, 256);
    hipLaunchKernelGGL(fsplit_k, dim3(42, 8, 16), dim3(256), 0, stream, features, Fh, Fl);
    hipLaunchKernelGGL(pool_k, dim3(16, 16), dim3(256), 0, stream, features, pooled);
    hipLaunchKernelGGL(head2_k, dim3(1), dim3(128), 0, stream, pooled, clw, clb, svw, svb, out);
    hipLaunchKernelGGL((convk<256, 512, 128, 128, 512, 2, 4, 1>), dim3(336, 2), dim3(512), 0, stream,
                       Fh, Fl, w1h, w1l, sh1, ZF, a1h, a1l, (float*)nullptr);
    hipLaunchKernelGGL((convk<128, 256, 64, 128, 256, 1, 4, 0>), dim3(336, 2), dim3(256), 0, stream,
                       a1h, a1l, w2h, w2l, sh2, ZA, (f16*)nullptr, (f16*)nullptr, act2);
    hipLaunchKernelGGL(dec_k, dim3(42), dim3(256), 0, stream, act2, c3w, c3b, bxs, cnf, clsv);
    hipLaunchKernelGGL(nms_k, dim3(16), dim3(256), 0, stream, bxs, cnf, clsv, out);
}